// Round 5
// baseline (87.011 us; speedup 1.0000x reference)
//
#include <hip/hip_runtime.h>
#include <math.h>

#define B_ 2
#define T_ 2048
#define D_ 512
#define H_ 16
#define DH 32
#define L_ 64
#define C_ 32
#define BH 32
#define NC 1024   // total chunks
#define VTP 72    // LDS row stride (ushorts) for chunk kernels

typedef __attribute__((ext_vector_type(8))) short bf16x8;
typedef __attribute__((ext_vector_type(4))) float f32x4;
typedef __attribute__((ext_vector_type(4))) unsigned short u16x4;

#define AS1 __attribute__((address_space(1)))
#define AS3 __attribute__((address_space(3)))

__device__ __forceinline__ float bf2f(unsigned short u) {
    union { float f; unsigned int i; } v; v.i = ((unsigned int)u) << 16; return v.f;
}
__device__ __forceinline__ unsigned short f2bf(float f) {
    union { float f; unsigned int u; } v; v.f = f;
    unsigned int u = v.u;
    unsigned int r = u + 0x7FFFu + ((u >> 16) & 1u);
    return (unsigned short)(r >> 16);
}
__device__ __forceinline__ bf16x8 phi_frag(bf16x8 in) {
    bf16x8 r;
    #pragma unroll
    for (int i = 0; i < 8; ++i) {
        float f = bf2f((unsigned short)in[i]);
        f = f > 0.f ? f + 1.f : __expf(f);
        r[i] = (short)f2bf(f);
    }
    return r;
}
__device__ __forceinline__ void gload_lds16(const unsigned short* g, unsigned short* l) {
    __builtin_amdgcn_global_load_lds((const AS1 unsigned int*)g, (AS3 unsigned int*)l, 16, 0, 0);
}

// One kernel converts all three fp32 inputs to bf16 (segments in float4 units).
__global__ __launch_bounds__(256) void convert_all(const float* __restrict__ x,
                                                   const float* __restrict__ wq,
                                                   const float* __restrict__ wo,
                                                   unsigned short* __restrict__ xb,
                                                   unsigned short* __restrict__ wqb,
                                                   unsigned short* __restrict__ wob)
{
    int i = blockIdx.x * 256 + threadIdx.x;   // 0 .. 786431
    const float* src; unsigned short* dst; int off;
    if (i < 524288)      { src = x;  dst = xb;  off = i; }
    else if (i < 720896) { src = wq; dst = wqb; off = i - 524288; }
    else                 { src = wo; dst = wob; off = i - 720896; }
    float4 v = ((const float4*)src)[off];
    u16x4 o;
    o.x = f2bf(v.x); o.y = f2bf(v.y); o.z = f2bf(v.z); o.w = f2bf(v.w);
    ((u16x4*)dst)[off] = o;
}

// C[m][n] = sum_k A[m][k]*W[n][k]; BMx128 tile, 4 waves (2x2), 16x16x32 bf16 MFMA.
// global_load_lds width-16 staging into LINEAR LDS tiles (m97 structure).
template<int BM, bool OUT_BF16>
__global__ __launch_bounds__(256) void gemm_bf16_nt(const unsigned short* __restrict__ A,
                                                    const unsigned short* __restrict__ W,
                                                    void* __restrict__ Cout,
                                                    int M, int N, int K)
{
    constexpr int MF = BM / 32;   // m-fragments per wave
    __shared__ unsigned short As[BM][32];
    __shared__ unsigned short Bs[128][32];
    const int tid = threadIdx.x;
    const int lane = tid & 63;
    const int wave = tid >> 6;
    const int wr = wave >> 1;
    const int wc = wave & 1;
    const size_t bm = (size_t)blockIdx.x * BM;
    const size_t bn = (size_t)blockIdx.y * 128;

    const int lrow = lane >> 2;
    const int lcol = (lane & 3) * 8;
    const unsigned short* ag0 = A + (bm + wave * (BM / 4) + lrow) * (size_t)K + lcol;
    unsigned short* al0 = &As[wave * (BM / 4)][0];
    const unsigned short* bg0 = W + (bn + wave * 32 + lrow) * (size_t)K + lcol;
    const unsigned short* bg1 = bg0 + (size_t)16 * K;
    unsigned short* bl0 = &Bs[wave * 32][0];
    unsigned short* bl1 = &Bs[wave * 32 + 16][0];

    f32x4 acc[MF][4];
    #pragma unroll
    for (int m = 0; m < MF; ++m)
        #pragma unroll
        for (int n = 0; n < 4; ++n)
            acc[m][n] = (f32x4){0.f, 0.f, 0.f, 0.f};

    const int rr = lane & 15;
    const int kb = (lane >> 4) * 8;

    for (int k0 = 0; k0 < K; k0 += 32) {
        gload_lds16(ag0 + k0, al0);
        if constexpr (BM == 128) gload_lds16(ag0 + (size_t)16 * K + k0, al0 + 16 * 32);
        gload_lds16(bg0 + k0, bl0);
        gload_lds16(bg1 + k0, bl1);
        __syncthreads();
        bf16x8 af[MF], bfr[4];
        #pragma unroll
        for (int m = 0; m < MF; ++m) af[m] = *(const bf16x8*)&As[wr * (BM / 2) + m * 16 + rr][kb];
        #pragma unroll
        for (int n = 0; n < 4; ++n) bfr[n] = *(const bf16x8*)&Bs[wc * 64 + n * 16 + rr][kb];
        #pragma unroll
        for (int m = 0; m < MF; ++m)
            #pragma unroll
            for (int n = 0; n < 4; ++n)
                acc[m][n] = __builtin_amdgcn_mfma_f32_16x16x32_bf16(af[m], bfr[n], acc[m][n], 0, 0, 0);
        __syncthreads();
    }

    const int cr = (lane >> 4) * 4;
    const int cc = lane & 15;
    #pragma unroll
    for (int m = 0; m < MF; ++m)
        #pragma unroll
        for (int n = 0; n < 4; ++n)
            #pragma unroll
            for (int j = 0; j < 4; ++j) {
                size_t row = bm + wr * (BM / 2) + m * 16 + cr + j;
                size_t col = bn + wc * 64 + n * 16 + cc;
                float v = acc[m][n][j];
                if (OUT_BF16) ((unsigned short*)Cout)[row * N + col] = f2bf(v);
                else          ((float*)Cout)[row * N + col] = v;
            }
}

// Per-chunk ST[e][d] = sum_t v_ext[t][e]*phi(k)[t][d], e=0..32 (row 32 = ksum).
__global__ __launch_bounds__(256) void chunk_sum(const unsigned short* __restrict__ qkv,
                                                 float* __restrict__ cSf)
{
    __shared__ unsigned short Kt[4][DH][VTP];
    __shared__ unsigned short Vt[4][48][VTP];
    const int tid = threadIdx.x;
    const int lane = tid & 63;
    const int wave = tid >> 6;
    const int chunk = blockIdx.x * 4 + wave;
    const int c = chunk & 31;
    const int h = (chunk >> 5) & 15;
    const int b = chunk >> 9;
    const size_t rowbase = ((size_t)(b * T_ + c * L_)) * (3 * D_) + h * DH;
    const int half = lane & 1;

    #pragma unroll
    for (int it = 0; it < 2; ++it) {
        int t = (lane >> 1) + it * 32;
        const unsigned short* kp = qkv + rowbase + (size_t)t * (3 * D_) + D_ + half * 16;
        const unsigned short* vp = qkv + rowbase + (size_t)t * (3 * D_) + 2 * D_ + half * 16;
        bf16x8 k0 = phi_frag(*(const bf16x8*)kp);
        bf16x8 k1 = phi_frag(*(const bf16x8*)(kp + 8));
        bf16x8 v0 = *(const bf16x8*)vp;
        bf16x8 v1 = *(const bf16x8*)(vp + 8);
        #pragma unroll
        for (int i = 0; i < 8; ++i) {
            Kt[wave][half * 16 + i][t]     = (unsigned short)k0[i];
            Kt[wave][half * 16 + 8 + i][t] = (unsigned short)k1[i];
            Vt[wave][half * 16 + i][t]     = (unsigned short)v0[i];
            Vt[wave][half * 16 + 8 + i][t] = (unsigned short)v1[i];
        }
    }
    Vt[wave][32][lane] = 0x3F80;   // ones row

    const int fr = lane & 15;
    const int fg = lane >> 4;
    f32x4 acc[3][2];
    #pragma unroll
    for (int m = 0; m < 3; ++m)
        #pragma unroll
        for (int n = 0; n < 2; ++n)
            acc[m][n] = (f32x4){0.f, 0.f, 0.f, 0.f};

    #pragma unroll
    for (int ks = 0; ks < 2; ++ks) {
        int toff = fg * 8 + ks * 32;
        bf16x8 av[3], bk[2];
        #pragma unroll
        for (int m = 0; m < 3; ++m) av[m] = *(const bf16x8*)&Vt[wave][m * 16 + fr][toff];
        #pragma unroll
        for (int n = 0; n < 2; ++n) bk[n] = *(const bf16x8*)&Kt[wave][n * 16 + fr][toff];
        #pragma unroll
        for (int m = 0; m < 3; ++m)
            #pragma unroll
            for (int n = 0; n < 2; ++n)
                acc[m][n] = __builtin_amdgcn_mfma_f32_16x16x32_bf16(av[m], bk[n], acc[m][n], 0, 0, 0);
    }

    float* outp = cSf + (size_t)chunk * (48 * 32);
    #pragma unroll
    for (int m = 0; m < 2; ++m)
        #pragma unroll
        for (int n = 0; n < 2; ++n)
            #pragma unroll
            for (int r = 0; r < 4; ++r)
                outp[(m * 16 + fg * 4 + r) * 32 + n * 16 + fr] = acc[m][n][r];
    if (fg == 0) {
        #pragma unroll
        for (int n = 0; n < 2; ++n)
            outp[32 * 32 + n * 16 + fr] = acc[2][n][0];
    }
}

// Per-chunk output via MFMA; exclusive chunk-prefix folded in (reads cSf directly).
// 2 waves per chunk (row halves), 2 chunks per block.
__global__ __launch_bounds__(256) void chunk_out(const unsigned short* __restrict__ qkv,
                                                 const float* __restrict__ cSf,
                                                 unsigned short* __restrict__ attn)
{
    __shared__ unsigned short Vt[2][48][VTP];
    __shared__ unsigned short Am[4][32][VTP];
    const int tid = threadIdx.x;
    const int lane = tid & 63;
    const int wave = tid >> 6;
    const int ci = wave >> 1;
    const int wh = wave & 1;
    const int chunk = blockIdx.x * 2 + ci;
    const int c = chunk & 31;
    const int h = (chunk >> 5) & 15;
    const int b = chunk >> 9;
    const size_t rowbase = ((size_t)(b * T_ + c * L_)) * (3 * D_) + h * DH;
    const int fr = lane & 15;
    const int fg = lane >> 4;

    {
        int t = wh * 32 + (lane >> 1);
        int half = lane & 1;
        const unsigned short* vp = qkv + rowbase + (size_t)t * (3 * D_) + 2 * D_ + half * 16;
        bf16x8 v0 = *(const bf16x8*)vp;
        bf16x8 v1 = *(const bf16x8*)(vp + 8);
        #pragma unroll
        for (int i = 0; i < 8; ++i) {
            Vt[ci][half * 16 + i][t]     = (unsigned short)v0[i];
            Vt[ci][half * 16 + 8 + i][t] = (unsigned short)v1[i];
        }
        if (half == 0) Vt[ci][32][t] = 0x3F80;
    }

    // exclusive prefix state fragments, summed in f32 from per-chunk cSf tiles
    float pf[3][8];
    #pragma unroll
    for (int n = 0; n < 3; ++n)
        #pragma unroll
        for (int i = 0; i < 8; ++i) pf[n][i] = 0.f;
    {
        const size_t chunkbase = (size_t)(chunk & ~31);
        for (int j = 0; j < c; ++j) {
            const float* sp = cSf + (chunkbase + j) * (48 * 32);
            #pragma unroll
            for (int n = 0; n < 3; ++n) {
                f32x4 lo = *(const f32x4*)&sp[(n * 16 + fr) * 32 + fg * 8];
                f32x4 hi = *(const f32x4*)&sp[(n * 16 + fr) * 32 + fg * 8 + 4];
                #pragma unroll
                for (int i = 0; i < 4; ++i) { pf[n][i] += lo[i]; pf[n][4 + i] += hi[i]; }
            }
        }
    }
    bf16x8 bkv[3];
    #pragma unroll
    for (int n = 0; n < 3; ++n)
        #pragma unroll
        for (int i = 0; i < 8; ++i) bkv[n][i] = (short)f2bf(pf[n][i]);

    bf16x8 aq[2];
    #pragma unroll
    for (int mm = 0; mm < 2; ++mm) {
        int m = wh * 2 + mm;
        const unsigned short* qp = qkv + rowbase + (size_t)(m * 16 + fr) * (3 * D_) + fg * 8;
        aq[mm] = phi_frag(*(const bf16x8*)qp);
    }
    bf16x8 bk[4];
    const int nmax = wh * 2 + 1;
    #pragma unroll
    for (int n = 0; n < 4; ++n) {
        if (n <= nmax) {
            const unsigned short* kp = qkv + rowbase + (size_t)(n * 16 + fr) * (3 * D_) + D_ + fg * 8;
            bk[n] = phi_frag(*(const bf16x8*)kp);
        }
    }

    f32x4 zero = (f32x4){0.f, 0.f, 0.f, 0.f};
    f32x4 acc[2][3];
    #pragma unroll
    for (int mm = 0; mm < 2; ++mm)
        #pragma unroll
        for (int n = 0; n < 3; ++n)
            acc[mm][n] = __builtin_amdgcn_mfma_f32_16x16x32_bf16(aq[mm], bkv[n], zero, 0, 0, 0);

    #pragma unroll
    for (int mm = 0; mm < 2; ++mm) {
        int m = wh * 2 + mm;
        #pragma unroll
        for (int n = 0; n < 4; ++n) {
            if (n <= m) {
                f32x4 s = __builtin_amdgcn_mfma_f32_16x16x32_bf16(aq[mm], bk[n], zero, 0, 0, 0);
                #pragma unroll
                for (int r = 0; r < 4; ++r) {
                    unsigned short v = f2bf(s[r]);
                    if (n == m && fr > fg * 4 + r) v = 0;
                    Am[wave][mm * 16 + fg * 4 + r][n * 16 + fr] = v;
                }
            }
        }
    }
    {
        int zc = wh ? 48 : 16;
        *(uint2*)&Am[wave][fr][zc + fg * 4] = (uint2){0u, 0u};
    }
    __syncthreads();

    #pragma unroll
    for (int ks = 0; ks < 2; ++ks) {
        if (ks <= wh) {
            bf16x8 bv[3];
            #pragma unroll
            for (int n = 0; n < 3; ++n)
                bv[n] = *(const bf16x8*)&Vt[ci][n * 16 + fr][fg * 8 + ks * 32];
            #pragma unroll
            for (int mm = 0; mm < 2; ++mm) {
                bf16x8 aa = *(const bf16x8*)&Am[wave][mm * 16 + fr][fg * 8 + ks * 32];
                #pragma unroll
                for (int n = 0; n < 3; ++n)
                    acc[mm][n] = __builtin_amdgcn_mfma_f32_16x16x32_bf16(aa, bv[n], acc[mm][n], 0, 0, 0);
            }
        }
    }

    #pragma unroll
    for (int mm = 0; mm < 2; ++mm) {
        float dn[4];
        #pragma unroll
        for (int r = 0; r < 4; ++r)
            dn[r] = __shfl(acc[mm][2][r], lane & 48);
        #pragma unroll
        for (int r = 0; r < 4; ++r) {
            float inv = 1.0f / fmaxf(dn[r], 1e-6f);
            #pragma unroll
            for (int n = 0; n < 2; ++n)
                Am[wave][mm * 16 + fg * 4 + r][n * 16 + fr] = f2bf(acc[mm][n][r] * inv);
        }
    }
    {
        int lrow = lane >> 1;
        int half = lane & 1;
        uint4 q0 = *(const uint4*)&Am[wave][lrow][half * 16];
        uint4 q1 = *(const uint4*)&Am[wave][lrow][half * 16 + 8];
        size_t grow = (size_t)(b * T_ + c * L_ + wh * 32 + lrow);
        unsigned short* dst = attn + grow * D_ + h * DH + half * 16;
        *(uint4*)dst = q0;
        *(uint4*)(dst + 8) = q1;
    }
}

extern "C" void kernel_launch(void* const* d_in, const int* in_sizes, int n_in,
                              void* d_out, int out_size, void* d_ws, size_t ws_size,
                              hipStream_t stream) {
    const float* x     = (const float*)d_in[0];
    const float* w_qkv = (const float*)d_in[1];
    const float* w_out = (const float*)d_in[2];
    float* out = (float*)d_out;

    char* ws = (char*)d_ws;
    unsigned short* qkvb  = (unsigned short*)ws;                 // 12,582,912 B
    unsigned short* attnb = (unsigned short*)(ws + 12582912);    //  4,194,304 B
    unsigned short* xb    = (unsigned short*)(ws + 16777216);    //  4,194,304 B
    unsigned short* wqb   = (unsigned short*)(ws + 20971520);    //  1,572,864 B
    unsigned short* wob   = (unsigned short*)(ws + 22544384);    //    524,288 B
    float* cSf            = (float*)(ws + 23068672);             //  6,291,456 B  [1024][48][32] f32
    // total 29,360,128 B

    convert_all<<<3072, 256, 0, stream>>>(x, w_qkv, w_out, xb, wqb, wob);

    dim3 g1(4096 / 128, 1536 / 128);
    gemm_bf16_nt<128, true><<<g1, 256, 0, stream>>>(xb, wqb, qkvb, 4096, 1536, 512);

    chunk_sum<<<NC / 4, 256, 0, stream>>>(qkvb, cSf);
    chunk_out<<<NC / 2, 256, 0, stream>>>(qkvb, cSf, attnb);

    dim3 g2(4096 / 64, 512 / 128);
    gemm_bf16_nt<64, false><<<g2, 256, 0, stream>>>(attnb, wob, out, 4096, 512, 512);
}

// Round 6
// 52.270 us; speedup vs baseline: 1.6646x; 1.6646x over previous
//
#include <hip/hip_runtime.h>
#include <math.h>

#define B_ 2
#define T_ 2048
#define D_ 512
#define H_ 16
#define DH 32
#define L_ 64
#define C_ 32
#define BH 32
#define NC 1024   // total chunks
#define VTP 72    // LDS row stride (ushorts) for chunk kernels

typedef __attribute__((ext_vector_type(8))) short bf16x8;
typedef __attribute__((ext_vector_type(4))) float f32x4;
typedef __attribute__((ext_vector_type(4))) unsigned short u16x4;

#define AS1 __attribute__((address_space(1)))
#define AS3 __attribute__((address_space(3)))

__device__ __forceinline__ float bf2f(unsigned short u) {
    union { float f; unsigned int i; } v; v.i = ((unsigned int)u) << 16; return v.f;
}
__device__ __forceinline__ unsigned short f2bf(float f) {
    union { float f; unsigned int u; } v; v.f = f;
    unsigned int u = v.u;
    unsigned int r = u + 0x7FFFu + ((u >> 16) & 1u);
    return (unsigned short)(r >> 16);
}
__device__ __forceinline__ bf16x8 phi_frag(bf16x8 in) {
    bf16x8 r;
    #pragma unroll
    for (int i = 0; i < 8; ++i) {
        float f = bf2f((unsigned short)in[i]);
        f = f > 0.f ? f + 1.f : __expf(f);
        r[i] = (short)f2bf(f);
    }
    return r;
}
__device__ __forceinline__ void gload_lds16(const unsigned short* g, unsigned short* l) {
    __builtin_amdgcn_global_load_lds((const AS1 unsigned int*)g, (AS3 unsigned int*)l, 16, 0, 0);
}

// One kernel converts all three fp32 inputs to bf16 (segments in float4 units).
__global__ __launch_bounds__(256) void convert_all(const float* __restrict__ x,
                                                   const float* __restrict__ wq,
                                                   const float* __restrict__ wo,
                                                   unsigned short* __restrict__ xb,
                                                   unsigned short* __restrict__ wqb,
                                                   unsigned short* __restrict__ wob)
{
    int i = blockIdx.x * 256 + threadIdx.x;   // 0 .. 786431
    const float* src; unsigned short* dst; int off;
    if (i < 524288)      { src = x;  dst = xb;  off = i; }
    else if (i < 720896) { src = wq; dst = wqb; off = i - 524288; }
    else                 { src = wo; dst = wob; off = i - 720896; }
    float4 v = ((const float4*)src)[off];
    u16x4 o;
    o.x = f2bf(v.x); o.y = f2bf(v.y); o.z = f2bf(v.z); o.w = f2bf(v.w);
    ((u16x4*)dst)[off] = o;
}

// C[m][n] = sum_k A[m][k]*W[n][k]; BMx128 tile, 4 waves (2x2), 16x16x32 bf16 MFMA.
// 2-phase double-buffered: stage tile k+1 via global_load_lds before computing
// tile k; single __syncthreads per K-step (vmcnt0+lgkmcnt0+barrier drain).
template<int BM, bool OUT_BF16>
__global__ __launch_bounds__(256) void gemm_bf16_nt(const unsigned short* __restrict__ A,
                                                    const unsigned short* __restrict__ W,
                                                    void* __restrict__ Cout,
                                                    int M, int N, int K)
{
    constexpr int MF = BM / 32;   // m-fragments per wave
    __shared__ unsigned short As[2][BM][32];
    __shared__ unsigned short Bs[2][128][32];
    const int tid = threadIdx.x;
    const int lane = tid & 63;
    const int wave = tid >> 6;
    const int wr = wave >> 1;
    const int wc = wave & 1;
    const size_t bm = (size_t)blockIdx.x * BM;
    const size_t bn = (size_t)blockIdx.y * 128;

    const int lrow = lane >> 2;
    const int lcol = (lane & 3) * 8;
    const unsigned short* ag0 = A + (bm + wave * (BM / 4) + lrow) * (size_t)K + lcol;
    const unsigned short* bg0 = W + (bn + wave * 32 + lrow) * (size_t)K + lcol;
    const unsigned short* bg1 = bg0 + (size_t)16 * K;

    auto stage = [&](int buf, int k0) {
        gload_lds16(ag0 + k0, &As[buf][wave * (BM / 4)][0]);
        if constexpr (BM == 128) gload_lds16(ag0 + (size_t)16 * K + k0, &As[buf][wave * (BM / 4) + 16][0]);
        gload_lds16(bg0 + k0, &Bs[buf][wave * 32][0]);
        gload_lds16(bg1 + k0, &Bs[buf][wave * 32 + 16][0]);
    };

    f32x4 acc[MF][4];
    #pragma unroll
    for (int m = 0; m < MF; ++m)
        #pragma unroll
        for (int n = 0; n < 4; ++n)
            acc[m][n] = (f32x4){0.f, 0.f, 0.f, 0.f};

    const int rr = lane & 15;
    const int kb = (lane >> 4) * 8;

    stage(0, 0);
    __syncthreads();
    int cur = 0;
    for (int k0 = 0; k0 < K; k0 += 32) {
        if (k0 + 32 < K) stage(cur ^ 1, k0 + 32);
        bf16x8 af[MF], bfr[4];
        #pragma unroll
        for (int m = 0; m < MF; ++m) af[m] = *(const bf16x8*)&As[cur][wr * (BM / 2) + m * 16 + rr][kb];
        #pragma unroll
        for (int n = 0; n < 4; ++n) bfr[n] = *(const bf16x8*)&Bs[cur][wc * 64 + n * 16 + rr][kb];
        #pragma unroll
        for (int m = 0; m < MF; ++m)
            #pragma unroll
            for (int n = 0; n < 4; ++n)
                acc[m][n] = __builtin_amdgcn_mfma_f32_16x16x32_bf16(af[m], bfr[n], acc[m][n], 0, 0, 0);
        __syncthreads();
        cur ^= 1;
    }

    const int cr = (lane >> 4) * 4;
    const int cc = lane & 15;
    #pragma unroll
    for (int m = 0; m < MF; ++m)
        #pragma unroll
        for (int n = 0; n < 4; ++n)
            #pragma unroll
            for (int j = 0; j < 4; ++j) {
                size_t row = bm + wr * (BM / 2) + m * 16 + cr + j;
                size_t col = bn + wc * 64 + n * 16 + cc;
                float v = acc[m][n][j];
                if (OUT_BF16) ((unsigned short*)Cout)[row * N + col] = f2bf(v);
                else          ((float*)Cout)[row * N + col] = v;
            }
}

// Per-chunk ST[e][d] = sum_t v_ext[t][e]*phi(k)[t][d], e=0..32 (row 32 = ksum).
__global__ __launch_bounds__(256) void chunk_sum(const unsigned short* __restrict__ qkv,
                                                 float* __restrict__ cSf)
{
    __shared__ unsigned short Kt[4][DH][VTP];
    __shared__ unsigned short Vt[4][48][VTP];
    const int tid = threadIdx.x;
    const int lane = tid & 63;
    const int wave = tid >> 6;
    const int chunk = blockIdx.x * 4 + wave;
    const int c = chunk & 31;
    const int h = (chunk >> 5) & 15;
    const int b = chunk >> 9;
    const size_t rowbase = ((size_t)(b * T_ + c * L_)) * (3 * D_) + h * DH;
    const int half = lane & 1;

    #pragma unroll
    for (int it = 0; it < 2; ++it) {
        int t = (lane >> 1) + it * 32;
        const unsigned short* kp = qkv + rowbase + (size_t)t * (3 * D_) + D_ + half * 16;
        const unsigned short* vp = qkv + rowbase + (size_t)t * (3 * D_) + 2 * D_ + half * 16;
        bf16x8 k0 = phi_frag(*(const bf16x8*)kp);
        bf16x8 k1 = phi_frag(*(const bf16x8*)(kp + 8));
        bf16x8 v0 = *(const bf16x8*)vp;
        bf16x8 v1 = *(const bf16x8*)(vp + 8);
        #pragma unroll
        for (int i = 0; i < 8; ++i) {
            Kt[wave][half * 16 + i][t]     = (unsigned short)k0[i];
            Kt[wave][half * 16 + 8 + i][t] = (unsigned short)k1[i];
            Vt[wave][half * 16 + i][t]     = (unsigned short)v0[i];
            Vt[wave][half * 16 + 8 + i][t] = (unsigned short)v1[i];
        }
    }
    Vt[wave][32][lane] = 0x3F80;   // ones row

    const int fr = lane & 15;
    const int fg = lane >> 4;
    f32x4 acc[3][2];
    #pragma unroll
    for (int m = 0; m < 3; ++m)
        #pragma unroll
        for (int n = 0; n < 2; ++n)
            acc[m][n] = (f32x4){0.f, 0.f, 0.f, 0.f};

    #pragma unroll
    for (int ks = 0; ks < 2; ++ks) {
        int toff = fg * 8 + ks * 32;
        bf16x8 av[3], bk[2];
        #pragma unroll
        for (int m = 0; m < 3; ++m) av[m] = *(const bf16x8*)&Vt[wave][m * 16 + fr][toff];
        #pragma unroll
        for (int n = 0; n < 2; ++n) bk[n] = *(const bf16x8*)&Kt[wave][n * 16 + fr][toff];
        #pragma unroll
        for (int m = 0; m < 3; ++m)
            #pragma unroll
            for (int n = 0; n < 2; ++n)
                acc[m][n] = __builtin_amdgcn_mfma_f32_16x16x32_bf16(av[m], bk[n], acc[m][n], 0, 0, 0);
    }

    float* outp = cSf + (size_t)chunk * (48 * 32);
    #pragma unroll
    for (int m = 0; m < 2; ++m)
        #pragma unroll
        for (int n = 0; n < 2; ++n)
            #pragma unroll
            for (int r = 0; r < 4; ++r)
                outp[(m * 16 + fg * 4 + r) * 32 + n * 16 + fr] = acc[m][n][r];
    if (fg == 0) {
        #pragma unroll
        for (int n = 0; n < 2; ++n)
            outp[32 * 32 + n * 16 + fr] = acc[2][n][0];
    }
}

// Exclusive prefix over chunks; emit bf16 state cSt[chunk][e][d].
// All 32 loads issued up front (independent), then register prefix + stores.
__global__ __launch_bounds__(256) void chunk_scan(const float* __restrict__ cSf,
                                                  unsigned short* __restrict__ cSt)
{
    int idx = blockIdx.x * 256 + threadIdx.x;     // 32*33*32 = 33792 exactly
    int bh = idx / (33 * 32);
    int r  = idx % (33 * 32);
    const float* src = cSf + (size_t)bh * C_ * (48 * 32) + r;
    unsigned short* dst = cSt + (size_t)bh * C_ * (48 * 32) + r;
    float v[C_];
    #pragma unroll
    for (int c = 0; c < C_; ++c) v[c] = src[(size_t)c * (48 * 32)];
    float acc = 0.f;
    #pragma unroll
    for (int c = 0; c < C_; ++c) {
        dst[(size_t)c * (48 * 32)] = f2bf(acc);
        acc += v[c];
    }
}

// Per-chunk output via MFMA. 2 waves per chunk (row halves), 2 chunks per block.
__global__ __launch_bounds__(256) void chunk_out(const unsigned short* __restrict__ qkv,
                                                 const unsigned short* __restrict__ cSt,
                                                 unsigned short* __restrict__ attn)
{
    __shared__ unsigned short Vt[2][48][VTP];
    __shared__ unsigned short Am[4][32][VTP];
    const int tid = threadIdx.x;
    const int lane = tid & 63;
    const int wave = tid >> 6;
    const int ci = wave >> 1;
    const int wh = wave & 1;
    const int chunk = blockIdx.x * 2 + ci;
    const int c = chunk & 31;
    const int h = (chunk >> 5) & 15;
    const int b = chunk >> 9;
    const size_t rowbase = ((size_t)(b * T_ + c * L_)) * (3 * D_) + h * DH;
    const int fr = lane & 15;
    const int fg = lane >> 4;

    {
        int t = wh * 32 + (lane >> 1);
        int half = lane & 1;
        const unsigned short* vp = qkv + rowbase + (size_t)t * (3 * D_) + 2 * D_ + half * 16;
        bf16x8 v0 = *(const bf16x8*)vp;
        bf16x8 v1 = *(const bf16x8*)(vp + 8);
        #pragma unroll
        for (int i = 0; i < 8; ++i) {
            Vt[ci][half * 16 + i][t]     = (unsigned short)v0[i];
            Vt[ci][half * 16 + 8 + i][t] = (unsigned short)v1[i];
        }
        if (half == 0) Vt[ci][32][t] = 0x3F80;
    }

    bf16x8 aq[2];
    #pragma unroll
    for (int mm = 0; mm < 2; ++mm) {
        int m = wh * 2 + mm;
        const unsigned short* qp = qkv + rowbase + (size_t)(m * 16 + fr) * (3 * D_) + fg * 8;
        aq[mm] = phi_frag(*(const bf16x8*)qp);
    }
    bf16x8 bk[4];
    const int nmax = wh * 2 + 1;
    #pragma unroll
    for (int n = 0; n < 4; ++n) {
        if (n <= nmax) {
            const unsigned short* kp = qkv + rowbase + (size_t)(n * 16 + fr) * (3 * D_) + D_ + fg * 8;
            bk[n] = phi_frag(*(const bf16x8*)kp);
        }
    }
    bf16x8 bkv[3];
    #pragma unroll
    for (int n = 0; n < 3; ++n)
        bkv[n] = *(const bf16x8*)&cSt[(size_t)chunk * 1536 + (size_t)(n * 16 + fr) * 32 + fg * 8];

    f32x4 zero = (f32x4){0.f, 0.f, 0.f, 0.f};
    f32x4 acc[2][3];
    #pragma unroll
    for (int mm = 0; mm < 2; ++mm)
        #pragma unroll
        for (int n = 0; n < 3; ++n)
            acc[mm][n] = __builtin_amdgcn_mfma_f32_16x16x32_bf16(aq[mm], bkv[n], zero, 0, 0, 0);

    #pragma unroll
    for (int mm = 0; mm < 2; ++mm) {
        int m = wh * 2 + mm;
        #pragma unroll
        for (int n = 0; n < 4; ++n) {
            if (n <= m) {
                f32x4 s = __builtin_amdgcn_mfma_f32_16x16x32_bf16(aq[mm], bk[n], zero, 0, 0, 0);
                #pragma unroll
                for (int r = 0; r < 4; ++r) {
                    unsigned short v = f2bf(s[r]);
                    if (n == m && fr > fg * 4 + r) v = 0;
                    Am[wave][mm * 16 + fg * 4 + r][n * 16 + fr] = v;
                }
            }
        }
    }
    {
        int zc = wh ? 48 : 16;
        *(uint2*)&Am[wave][fr][zc + fg * 4] = (uint2){0u, 0u};
    }
    __syncthreads();

    #pragma unroll
    for (int ks = 0; ks < 2; ++ks) {
        if (ks <= wh) {
            bf16x8 bv[3];
            #pragma unroll
            for (int n = 0; n < 3; ++n)
                bv[n] = *(const bf16x8*)&Vt[ci][n * 16 + fr][fg * 8 + ks * 32];
            #pragma unroll
            for (int mm = 0; mm < 2; ++mm) {
                bf16x8 aa = *(const bf16x8*)&Am[wave][mm * 16 + fr][fg * 8 + ks * 32];
                #pragma unroll
                for (int n = 0; n < 3; ++n)
                    acc[mm][n] = __builtin_amdgcn_mfma_f32_16x16x32_bf16(aa, bv[n], acc[mm][n], 0, 0, 0);
            }
        }
    }

    #pragma unroll
    for (int mm = 0; mm < 2; ++mm) {
        float dn[4];
        #pragma unroll
        for (int r = 0; r < 4; ++r)
            dn[r] = __shfl(acc[mm][2][r], lane & 48);
        #pragma unroll
        for (int r = 0; r < 4; ++r) {
            float inv = 1.0f / fmaxf(dn[r], 1e-6f);
            #pragma unroll
            for (int n = 0; n < 2; ++n)
                Am[wave][mm * 16 + fg * 4 + r][n * 16 + fr] = f2bf(acc[mm][n][r] * inv);
        }
    }
    {
        int lrow = lane >> 1;
        int half = lane & 1;
        uint4 q0 = *(const uint4*)&Am[wave][lrow][half * 16];
        uint4 q1 = *(const uint4*)&Am[wave][lrow][half * 16 + 8];
        size_t grow = (size_t)(b * T_ + c * L_ + wh * 32 + lrow);
        unsigned short* dst = attn + grow * D_ + h * DH + half * 16;
        *(uint4*)dst = q0;
        *(uint4*)(dst + 8) = q1;
    }
}

extern "C" void kernel_launch(void* const* d_in, const int* in_sizes, int n_in,
                              void* d_out, int out_size, void* d_ws, size_t ws_size,
                              hipStream_t stream) {
    const float* x     = (const float*)d_in[0];
    const float* w_qkv = (const float*)d_in[1];
    const float* w_out = (const float*)d_in[2];
    float* out = (float*)d_out;

    char* ws = (char*)d_ws;
    unsigned short* qkvb  = (unsigned short*)ws;                 // 12,582,912 B
    unsigned short* attnb = (unsigned short*)(ws + 12582912);    //  4,194,304 B
    unsigned short* xb    = (unsigned short*)(ws + 16777216);    //  4,194,304 B
    unsigned short* wqb   = (unsigned short*)(ws + 20971520);    //  1,572,864 B
    unsigned short* wob   = (unsigned short*)(ws + 22544384);    //    524,288 B
    float* cSf            = (float*)(ws + 23068672);             //  6,291,456 B  [1024][48][32] f32
    unsigned short* cSt   = (unsigned short*)(ws + 29360128);    //  3,145,728 B  [1024][48][32] bf16
    // total 32,505,856 B

    convert_all<<<3072, 256, 0, stream>>>(x, w_qkv, w_out, xb, wqb, wob);

    dim3 g1(4096 / 128, 1536 / 128);
    gemm_bf16_nt<128, true><<<g1, 256, 0, stream>>>(xb, wqb, qkvb, 4096, 1536, 512);

    chunk_sum<<<NC / 4, 256, 0, stream>>>(qkvb, cSf);
    chunk_scan<<<132, 256, 0, stream>>>(cSf, cSt);
    chunk_out<<<NC / 2, 256, 0, stream>>>(qkvb, cSt, attnb);

    dim3 g2(4096 / 64, 512 / 128);
    gemm_bf16_nt<64, false><<<g2, 256, 0, stream>>>(attnb, wob, out, 4096, 512, 512);
}